// Round 4
// baseline (62.332 us; speedup 1.0000x reference)
//
#include <hip/hip_runtime.h>

// Problem geometry (fixed by reference setup_inputs()):
//   src: [B=4, N=8192, 3] f32
//   dst: [B=4, S=2048, 3] f32
//   out: [B, N, S] f32 = softmax_S( exp( -0.5 * ||src_n - dst_s|| ) )
#define BB 4
#define NN 8192
#define SS 2048
#define ROWS 8   // rows (n-values) per block; dst coords stay in registers

#define L2E  1.4426950408889634f   // log2(e)
#define NL2E 0.7213475204444817f   // 0.5 * log2(e)

typedef float f32x4 __attribute__((ext_vector_type(4)));  // native vector for nontemporal builtin

// One block per ROWS consecutive (b, n) rows. 256 threads; each thread owns 8
// s-values (two groups of 4 consecutive -> float4 loads/stores), reused
// across ROWS rows. Output stored non-temporally (write-once stream).
__global__ __launch_bounds__(256)
void gauss_softmax_kernel(const float* __restrict__ src,
                          const float* __restrict__ dst,
                          float* __restrict__ out) {
    const int n0  = blockIdx.x * ROWS;
    const int b   = blockIdx.y;
    const int tid = threadIdx.x;

    const float* dstb = dst + (size_t)b * SS * 3;

    // Load this thread's 8 dst points once (registers), reuse across ROWS.
    float px[8], py[8], pz[8];
    #pragma unroll
    for (int k = 0; k < 2; ++k) {
        const int s0 = tid * 4 + k * 1024;  // 48B-aligned: tid*48 + k*12288
        const f32x4 p0 = *reinterpret_cast<const f32x4*>(dstb + (size_t)s0 * 3 + 0);
        const f32x4 p1 = *reinterpret_cast<const f32x4*>(dstb + (size_t)s0 * 3 + 4);
        const f32x4 p2 = *reinterpret_cast<const f32x4*>(dstb + (size_t)s0 * 3 + 8);
        px[k*4+0] = p0.x; py[k*4+0] = p0.y; pz[k*4+0] = p0.z;
        px[k*4+1] = p0.w; py[k*4+1] = p1.x; pz[k*4+1] = p1.y;
        px[k*4+2] = p1.z; py[k*4+2] = p1.w; pz[k*4+2] = p2.x;
        px[k*4+3] = p2.y; py[k*4+3] = p2.z; pz[k*4+3] = p2.w;
    }

    __shared__ float wsum[ROWS][4];
    const int lane = tid & 63;
    const int wid  = tid >> 6;

    float v[ROWS][8];

    #pragma unroll
    for (int r = 0; r < ROWS; ++r) {
        const size_t row = (size_t)(b * NN + n0 + r);
        const float sx = src[row * 3 + 0];
        const float sy = src[row * 3 + 1];
        const float sz = src[row * 3 + 2];

        float local = 0.0f;
        #pragma unroll
        for (int j = 0; j < 8; ++j) {
            const float dx = sx - px[j];
            const float dy = sy - py[j];
            const float dz = sz - pz[j];
            const float d2 = fmaxf(dx * dx + dy * dy + dz * dz, 1e-12f);
            const float dist = __builtin_amdgcn_sqrtf(d2);
            // exp(exp(-0.5*dist)) = exp2(L2E * exp2(-0.5*L2E*dist))
            const float inner = __builtin_amdgcn_exp2f(-NL2E * dist);
            const float t = __builtin_amdgcn_exp2f(L2E * inner);
            v[r][j] = t;
            local += t;
        }

        // wave64 butterfly reduce
        #pragma unroll
        for (int off = 32; off >= 1; off >>= 1)
            local += __shfl_down(local, off, 64);
        if (lane == 0) wsum[r][wid] = local;
    }

    __syncthreads();

    #pragma unroll
    for (int r = 0; r < ROWS; ++r) {
        const float inv = __builtin_amdgcn_rcpf(wsum[r][0] + wsum[r][1] +
                                                wsum[r][2] + wsum[r][3]);
        float* outp = out + (size_t)(b * NN + n0 + r) * SS;
        #pragma unroll
        for (int k = 0; k < 2; ++k) {
            const int s0 = tid * 4 + k * 1024;
            f32x4 o;
            o.x = v[r][k*4+0] * inv;
            o.y = v[r][k*4+1] * inv;
            o.z = v[r][k*4+2] * inv;
            o.w = v[r][k*4+3] * inv;
            __builtin_nontemporal_store(o, reinterpret_cast<f32x4*>(outp + s0));
        }
    }
}

extern "C" void kernel_launch(void* const* d_in, const int* in_sizes, int n_in,
                              void* d_out, int out_size, void* d_ws, size_t ws_size,
                              hipStream_t stream) {
    const float* src = (const float*)d_in[0];  // [4, 8192, 3]
    const float* dst = (const float*)d_in[1];  // [4, 2048, 3]
    float* out = (float*)d_out;                // [4, 8192, 2048]

    dim3 grid(NN / ROWS, BB);
    dim3 block(256);
    gauss_softmax_kernel<<<grid, block, 0, stream>>>(src, dst, out);
}

// Round 5
// 50.081 us; speedup vs baseline: 1.2446x; 1.2446x over previous
//
#include <hip/hip_runtime.h>

// Problem geometry (fixed by reference setup_inputs()):
//   src: [B=4, N=8192, 3] f32
//   dst: [B=4, S=2048, 3] f32
//   out: [B, N, S] f32 = softmax_S( exp( -0.5 * ||src_n - dst_s|| ) )
#define BB 4
#define NN 8192
#define SS 2048
#define ROWS_PER_WAVE 4   // each wave owns whole rows -> wave-local softmax sum

#define L2E  1.4426950408889634f   // log2(e)
#define NL2E 0.7213475204444817f   // 0.5 * log2(e)

typedef float f32x4 __attribute__((ext_vector_type(4)));

// Block = 4 waves, covers 16 consecutive rows of one batch.
// Stage dst into LDS as SoA (X/Y/Z, 24 KB) once; then each wave streams its
// rows independently: 32 elems/lane, wave-butterfly sum, float4 stores.
// No per-row __syncthreads; waves drift apart so compute/store overlap.
__global__ __launch_bounds__(256)
void gauss_softmax_kernel(const float* __restrict__ src,
                          const float* __restrict__ dst,
                          float* __restrict__ out) {
    __shared__ __align__(16) float X[SS];
    __shared__ __align__(16) float Y[SS];
    __shared__ __align__(16) float Z[SS];

    const int tid = threadIdx.x;
    const int b   = blockIdx.y;
    const int bx  = blockIdx.x;   // 0..511

    // ---- Stage dst -> LDS SoA (each thread: 8 points as 2 groups of 4) ----
    const float* dstb = dst + (size_t)b * SS * 3;
    #pragma unroll
    for (int k = 0; k < 2; ++k) {
        const int s0 = tid * 4 + k * 1024;  // 48B-aligned global, 16B-aligned LDS
        const f32x4 p0 = *reinterpret_cast<const f32x4*>(dstb + (size_t)s0 * 3 + 0);
        const f32x4 p1 = *reinterpret_cast<const f32x4*>(dstb + (size_t)s0 * 3 + 4);
        const f32x4 p2 = *reinterpret_cast<const f32x4*>(dstb + (size_t)s0 * 3 + 8);
        const f32x4 xs = {p0.x, p0.w, p1.z, p2.y};
        const f32x4 ys = {p0.y, p1.x, p1.w, p2.z};
        const f32x4 zs = {p0.z, p1.y, p2.x, p2.w};
        *reinterpret_cast<f32x4*>(X + s0) = xs;
        *reinterpret_cast<f32x4*>(Y + s0) = ys;
        *reinterpret_cast<f32x4*>(Z + s0) = zs;
    }
    __syncthreads();  // only barrier in the kernel

    const int wid  = tid >> 6;
    const int lane = tid & 63;
    const int nbase = bx * (4 * ROWS_PER_WAVE) + wid * ROWS_PER_WAVE;

    #pragma unroll
    for (int r = 0; r < ROWS_PER_WAVE; ++r) {
        const int n = nbase + r;
        const size_t row = (size_t)b * NN + n;
        const float sx = src[row * 3 + 0];
        const float sy = src[row * 3 + 1];
        const float sz = src[row * 3 + 2];

        float v[32];
        float sum = 0.0f;
        #pragma unroll
        for (int k = 0; k < 8; ++k) {
            const int p = k * 256 + lane * 4;   // 4 consecutive points
            const f32x4 xs = *reinterpret_cast<const f32x4*>(X + p);
            const f32x4 ys = *reinterpret_cast<const f32x4*>(Y + p);
            const f32x4 zs = *reinterpret_cast<const f32x4*>(Z + p);
            #pragma unroll
            for (int j = 0; j < 4; ++j) {
                const float dx = sx - xs[j];
                const float dy = sy - ys[j];
                const float dz = sz - zs[j];
                const float d2 = fmaxf(dx * dx + dy * dy + dz * dz, 1e-12f);
                const float dist = __builtin_amdgcn_sqrtf(d2);
                // exp(exp(-0.5*dist)) = exp2(L2E * exp2(-0.5*L2E*dist))
                const float inner = __builtin_amdgcn_exp2f(-NL2E * dist);
                const float t = __builtin_amdgcn_exp2f(L2E * inner);
                v[k * 4 + j] = t;
                sum += t;
            }
        }

        // Full-wave butterfly: every lane ends with the row total.
        #pragma unroll
        for (int off = 1; off < 64; off <<= 1)
            sum += __shfl_xor(sum, off, 64);
        const float inv = __builtin_amdgcn_rcpf(sum);

        float* outp = out + row * SS;
        #pragma unroll
        for (int k = 0; k < 8; ++k) {
            f32x4 o;
            o.x = v[k * 4 + 0] * inv;
            o.y = v[k * 4 + 1] * inv;
            o.z = v[k * 4 + 2] * inv;
            o.w = v[k * 4 + 3] * inv;
            *reinterpret_cast<f32x4*>(outp + k * 256 + lane * 4) = o;
        }
    }
}

extern "C" void kernel_launch(void* const* d_in, const int* in_sizes, int n_in,
                              void* d_out, int out_size, void* d_ws, size_t ws_size,
                              hipStream_t stream) {
    const float* src = (const float*)d_in[0];  // [4, 8192, 3]
    const float* dst = (const float*)d_in[1];  // [4, 2048, 3]
    float* out = (float*)d_out;                // [4, 8192, 2048]

    dim3 grid(NN / (4 * ROWS_PER_WAVE), BB);   // 512 x 4 blocks
    dim3 block(256);
    gauss_softmax_kernel<<<grid, block, 0, stream>>>(src, dst, out);
}

// Round 6
// 49.806 us; speedup vs baseline: 1.2515x; 1.0055x over previous
//
#include <hip/hip_runtime.h>

// Problem geometry (fixed by reference setup_inputs()):
//   src: [B=4, N=8192, 3] f32
//   dst: [B=4, S=2048, 3] f32
//   out: [B, N, S] f32 = softmax_S( exp( -0.5 * ||src_n - dst_s|| ) )
#define BB 4
#define NN 8192
#define SS 2048
#define ROWS 2   // rows per block, sized so VGPR <= 64 (8 waves/SIMD)

#define L2E  1.4426950408889634f   // log2(e)
#define NL2E 0.7213475204444817f   // 0.5 * log2(e)

typedef float f32x4 __attribute__((ext_vector_type(4)));

// One block per ROWS consecutive (b, n) rows. 256 threads; each thread owns 8
// s-values (two groups of 4 consecutive -> float4 loads/stores), dst coords
// register-resident (24 VGPR; dst is L1-resident so per-block reload is cheap).
// ROWS=2 keeps total VGPR <= 64 -> 8 waves/SIMD for max store/compute overlap.
__global__ __launch_bounds__(256, 8)
void gauss_softmax_kernel(const float* __restrict__ src,
                          const float* __restrict__ dst,
                          float* __restrict__ out) {
    const int n0  = blockIdx.x * ROWS;
    const int b   = blockIdx.y;
    const int tid = threadIdx.x;

    const float* dstb = dst + (size_t)b * SS * 3;

    // Load this thread's 8 dst points into registers (L1-hit after warmup).
    float px[8], py[8], pz[8];
    #pragma unroll
    for (int k = 0; k < 2; ++k) {
        const int s0 = tid * 4 + k * 1024;  // 48B-aligned: tid*48 + k*12288
        const f32x4 p0 = *reinterpret_cast<const f32x4*>(dstb + (size_t)s0 * 3 + 0);
        const f32x4 p1 = *reinterpret_cast<const f32x4*>(dstb + (size_t)s0 * 3 + 4);
        const f32x4 p2 = *reinterpret_cast<const f32x4*>(dstb + (size_t)s0 * 3 + 8);
        px[k*4+0] = p0.x; py[k*4+0] = p0.y; pz[k*4+0] = p0.z;
        px[k*4+1] = p0.w; py[k*4+1] = p1.x; pz[k*4+1] = p1.y;
        px[k*4+2] = p1.z; py[k*4+2] = p1.w; pz[k*4+2] = p2.x;
        px[k*4+3] = p2.y; py[k*4+3] = p2.z; pz[k*4+3] = p2.w;
    }

    __shared__ float wsum[ROWS][4];
    const int lane = tid & 63;
    const int wid  = tid >> 6;

    float v[ROWS][8];

    #pragma unroll
    for (int r = 0; r < ROWS; ++r) {
        const size_t row = (size_t)(b * NN + n0 + r);
        const float sx = src[row * 3 + 0];
        const float sy = src[row * 3 + 1];
        const float sz = src[row * 3 + 2];

        float local = 0.0f;
        #pragma unroll
        for (int j = 0; j < 8; ++j) {
            const float dx = sx - px[j];
            const float dy = sy - py[j];
            const float dz = sz - pz[j];
            const float d2 = fmaxf(dx * dx + dy * dy + dz * dz, 1e-12f);
            const float dist = __builtin_amdgcn_sqrtf(d2);
            // exp(exp(-0.5*dist)) = exp2(L2E * exp2(-0.5*L2E*dist))
            const float inner = __builtin_amdgcn_exp2f(-NL2E * dist);
            const float t = __builtin_amdgcn_exp2f(L2E * inner);
            v[r][j] = t;
            local += t;
        }

        // wave64 butterfly reduce
        #pragma unroll
        for (int off = 32; off >= 1; off >>= 1)
            local += __shfl_down(local, off, 64);
        if (lane == 0) wsum[r][wid] = local;
    }

    __syncthreads();

    #pragma unroll
    for (int r = 0; r < ROWS; ++r) {
        const float inv = __builtin_amdgcn_rcpf(wsum[r][0] + wsum[r][1] +
                                                wsum[r][2] + wsum[r][3]);
        float* outp = out + (size_t)(b * NN + n0 + r) * SS;
        #pragma unroll
        for (int k = 0; k < 2; ++k) {
            const int s0 = tid * 4 + k * 1024;
            f32x4 o;
            o.x = v[r][k*4+0] * inv;
            o.y = v[r][k*4+1] * inv;
            o.z = v[r][k*4+2] * inv;
            o.w = v[r][k*4+3] * inv;
            *reinterpret_cast<f32x4*>(outp + s0) = o;
        }
    }
}

extern "C" void kernel_launch(void* const* d_in, const int* in_sizes, int n_in,
                              void* d_out, int out_size, void* d_ws, size_t ws_size,
                              hipStream_t stream) {
    const float* src = (const float*)d_in[0];  // [4, 8192, 3]
    const float* dst = (const float*)d_in[1];  // [4, 2048, 3]
    float* out = (float*)d_out;                // [4, 8192, 2048]

    dim3 grid(NN / ROWS, BB);                  // 4096 x 4 blocks
    dim3 block(256);
    gauss_softmax_kernel<<<grid, block, 0, stream>>>(src, dst, out);
}